// Round 8
// baseline (301.063 us; speedup 1.0000x reference)
//
#include <hip/hip_runtime.h>

#define N_NODES 50000
#define N_EDGES 600000
#define D_IN 5
#define D_H 128
#define BN_EPS 1e-5f
#define SCAN_BLOCKS ((N_NODES + 255) / 256)   // 196
#define DEG_BLOCKS ((N_EDGES + 255) / 256)    // 2344
#define FIX_SCALE 16777216.0f                  // 2^24
#define FIX_INV   (1.0f / 16777216.0f)

typedef __bf16 bf16x8 __attribute__((ext_vector_type(8)));
typedef float  f32x4  __attribute__((ext_vector_type(4)));

__device__ inline unsigned short f2bfb(float f) {          // fp32 -> bf16 bits, RNE
    unsigned u = __builtin_bit_cast(unsigned, f);
    unsigned r = u + 0x7fffu + ((u >> 16) & 1u);
    return (unsigned short)(r >> 16);
}
__device__ inline float bflo(unsigned u) { return __builtin_bit_cast(float, u << 16); }
__device__ inline float bfhi(unsigned u) { return __builtin_bit_cast(float, u & 0xffff0000u); }

// ---------------------------------------------------------------------------
// Stage Bt[128][128] bf16 into LDS fragment-major: frag fid=ct*4+ks at
// fid*1024 bytes; lane l's 16 B at fid*1024+l*16.
// ---------------------------------------------------------------------------
__device__ inline void stage_b(const unsigned short* __restrict__ Bt,
                               uint4* __restrict__ lds, int t)
{
#pragma unroll
    for (int i = 0; i < 8; ++i) {
        int slot = i * 256 + t;          // 0..2047
        int fid = slot >> 6;
        int l = slot & 63;
        int row = (fid >> 2) * 16 + (l & 15);
        int boff = ((l >> 4) * 16 + (fid & 3) * 64) >> 1;   // in shorts
        lds[slot] = *(const uint4*)(Bt + row * D_H + boff);
    }
}

// ---------------------------------------------------------------------------
// Fused prep: [0,192) weight transpose+bf16; [192,192+SCAN_BLOCKS) BN0 stats;
// rest: per-edge u64 deg/count atomic + rank capture.
// ---------------------------------------------------------------------------
__global__ __launch_bounds__(256) void k_prep(const float* __restrict__ W2,
                                              const float* __restrict__ Wmu,
                                              const float* __restrict__ Wls,
                                              unsigned short* __restrict__ T2,
                                              unsigned short* __restrict__ Tmu,
                                              unsigned short* __restrict__ Tls,
                                              const float* __restrict__ h,
                                              float* __restrict__ stats0,
                                              const int* __restrict__ dst,
                                              const float* __restrict__ w,
                                              unsigned long long* __restrict__ degcnt,
                                              int* __restrict__ rank)
{
    __shared__ float ss[D_IN], sq[D_IN];
    int b = blockIdx.x;
    int t = threadIdx.x;
    if (b < 192) {
        int mat = b >> 6;
        int idx = (b & 63) * 256 + t;   // < 16384
        const float* W = (mat == 0) ? W2 : (mat == 1) ? Wmu : Wls;
        unsigned short* T = (mat == 0) ? T2 : (mat == 1) ? Tmu : Tls;
        int k = idx >> 7, n = idx & 127;
        T[n * D_H + k] = f2bfb(W[idx]);
    } else if (b < 192 + SCAN_BLOCKS) {
        if (t < D_IN) { ss[t] = 0.f; sq[t] = 0.f; }
        __syncthreads();
        int node = (b - 192) * 256 + t;
        float v[D_IN];
#pragma unroll
        for (int f = 0; f < D_IN; ++f)
            v[f] = (node < N_NODES) ? h[node * D_IN + f] : 0.f;
        int lane = t & 63;
#pragma unroll
        for (int f = 0; f < D_IN; ++f) {
            float s = v[f], q = v[f] * v[f];
            for (int off = 32; off > 0; off >>= 1) {
                s += __shfl_down(s, off);
                q += __shfl_down(q, off);
            }
            if (lane == 0) { atomicAdd(&ss[f], s); atomicAdd(&sq[f], q); }
        }
        __syncthreads();
        if (t < D_IN) {
            atomicAdd(&stats0[t], ss[t]);
            atomicAdd(&stats0[D_IN + t], sq[t]);
        }
    } else {
        int e = (b - 192 - SCAN_BLOCKS) * 256 + t;
        if (e < N_EDGES) {
            int d = dst[e];
            unsigned long long fx = (unsigned long long)(w[e] * FIX_SCALE + 0.5f);
            unsigned long long old = atomicAdd(degcnt + d, (1ull << 40) | fx);
            rank[e] = (int)(old >> 40);
        }
    }
}

// ---------------------------------------------------------------------------
// Scan pass 1: per-block sum of counts -> blocksums (raw); dis = rsqrt(deg+1)
// ---------------------------------------------------------------------------
__global__ __launch_bounds__(256) void k_scan1(const unsigned long long* __restrict__ degcnt,
                                               float* __restrict__ dis,
                                               int* __restrict__ blocksums)
{
    __shared__ int sm[256];
    int t = threadIdx.x;
    int i = blockIdx.x * 256 + t;
    int c = 0;
    if (i < N_NODES) {
        unsigned long long v = degcnt[i];
        c = (int)(v >> 40);
        float deg = (float)(v & ((1ull << 40) - 1)) * FIX_INV;
        dis[i] = rsqrtf(deg + 1.0f);
    }
    sm[t] = c;
    __syncthreads();
    for (int off = 128; off > 0; off >>= 1) {
        if (t < off) sm[t] += sm[t + off];
        __syncthreads();
    }
    if (t == 0) blocksums[blockIdx.x] = sm[0];
}

// ---------------------------------------------------------------------------
// Scan pass 2 (merged): every block redundantly scans the 196 raw blocksums
// in LDS to get its own prefix, then does its local node scan -> rowptr.
// ---------------------------------------------------------------------------
__global__ __launch_bounds__(256) void k_scan3(const unsigned long long* __restrict__ degcnt,
                                               int* __restrict__ rowptr,
                                               const int* __restrict__ blocksums)
{
    __shared__ int bs[256];
    __shared__ int sm[256];
    int t = threadIdx.x;
    // scan the block sums (inclusive)
    int bc = (t < SCAN_BLOCKS) ? blocksums[t] : 0;
    bs[t] = bc;
    __syncthreads();
    for (int off = 1; off < 256; off <<= 1) {
        int v = (t >= off) ? bs[t - off] : 0;
        __syncthreads();
        bs[t] += v;
        __syncthreads();
    }
    int prefix = (blockIdx.x == 0) ? 0 : bs[blockIdx.x - 1];
    if (blockIdx.x == SCAN_BLOCKS - 1 && t == 255)
        rowptr[N_NODES] = bs[SCAN_BLOCKS - 1];
    // local node scan
    int i = blockIdx.x * 256 + t;
    int c = (i < N_NODES) ? (int)(degcnt[i] >> 40) : 0;
    sm[t] = c;
    __syncthreads();
    for (int off = 1; off < 256; off <<= 1) {
        int v = (t >= off) ? sm[t - off] : 0;
        __syncthreads();
        sm[t] += v;
        __syncthreads();
    }
    if (i < N_NODES)
        rowptr[i] = prefix + sm[t] - c;
}

// ---------------------------------------------------------------------------
// Fill CSR, atomic-free: pos = rowptr[dst] + rank. csr = {src, dis[src]*w}
// ---------------------------------------------------------------------------
__global__ __launch_bounds__(256) void k_fill(const int* __restrict__ src,
                                              const int* __restrict__ dst,
                                              const float* __restrict__ w,
                                              const float* __restrict__ dis,
                                              const int* __restrict__ rowptr,
                                              const int* __restrict__ rank,
                                              int2* __restrict__ csr)
{
    int e = blockIdx.x * blockDim.x + threadIdx.x;
    if (e < N_EDGES) {
        int s = src[e], d = dst[e];
        float pn = dis[s] * w[e];
        int pos = rowptr[d] + rank[e];
        int2 pk;
        pk.x = s;
        pk.y = __builtin_bit_cast(int, pn);
        csr[pos] = pk;
    }
}

// ---------------------------------------------------------------------------
// Aggregate BN0(h) at width 5; agg rows padded to stride 8 for float4 loads.
// agg[n] = dis[n]*(dis[n]*bn(h[n]) + sum pn*bn(h[s]))
// ---------------------------------------------------------------------------
__global__ __launch_bounds__(256) void k_agg0(const float* __restrict__ h,
                                              const float* __restrict__ stats,
                                              const float* __restrict__ g0,
                                              const float* __restrict__ be0,
                                              const int* __restrict__ rowptr,
                                              const int2* __restrict__ csr,
                                              const float* __restrict__ dis,
                                              float* __restrict__ agg)
{
    int n = blockIdx.x * blockDim.x + threadIdx.x;
    if (n >= N_NODES) return;
    float sc[D_IN], sh[D_IN];
#pragma unroll
    for (int f = 0; f < D_IN; ++f) {
        float m = stats[f] * (1.0f / N_NODES);
        float var = stats[D_IN + f] * (1.0f / N_NODES) - m * m;
        sc[f] = rsqrtf(var + BN_EPS) * g0[f];
        sh[f] = be0[f] - m * sc[f];
    }
    float dn = dis[n];
    float acc[D_IN];
#pragma unroll
    for (int f = 0; f < D_IN; ++f)
        acc[f] = dn * (h[n * D_IN + f] * sc[f] + sh[f]);
    int e0 = rowptr[n], e1 = rowptr[n + 1];
    for (int e = e0; e < e1; ++e) {
        int2 pk = csr[e];
        int s = pk.x;
        float pn = __builtin_bit_cast(float, pk.y);
#pragma unroll
        for (int f = 0; f < D_IN; ++f)
            acc[f] += pn * (h[s * D_IN + f] * sc[f] + sh[f]);
    }
#pragma unroll
    for (int f = 0; f < D_IN; ++f)
        agg[(size_t)n * 8 + f] = dn * acc[f];
}

// ---------------------------------------------------------------------------
// Layer-1 stats ONLY: x1 = agg0 @ W1 + b1 computed on the fly (never stored).
// MUST be launched with exactly 512 blocks x 256 threads.
// ---------------------------------------------------------------------------
__global__ __launch_bounds__(256) void k_l1(const float* __restrict__ agg,
                                            const float* __restrict__ W1,
                                            const float* __restrict__ b1,
                                            float* __restrict__ stats)
{
    __shared__ float sm_s[D_H], sm_q[D_H];
    int t = threadIdx.x;
    if (t < D_H) { sm_s[t] = 0.f; sm_q[t] = 0.f; }
    __syncthreads();
    int idx0 = blockIdx.x * 256 + t;
    int f0 = (idx0 & 63) * 2;      // feature pair, constant per thread
    float wa[D_IN], wb[D_IN];
#pragma unroll
    for (int k = 0; k < D_IN; ++k) {
        wa[k] = W1[k * D_H + f0];
        wb[k] = W1[k * D_H + f0 + 1];
    }
    float ba = b1[f0], bb = b1[f0 + 1];
    float s0 = 0.f, q0 = 0.f, s1 = 0.f, q1 = 0.f;
    const int stride = 512 * 256;
    for (int idx = idx0; idx < N_NODES * 64; idx += stride) {
        int n = idx >> 6;
        const float* a = agg + (size_t)n * 8;
        float v0 = ba, v1 = bb;
#pragma unroll
        for (int k = 0; k < D_IN; ++k) { v0 += wa[k] * a[k]; v1 += wb[k] * a[k]; }
        s0 += v0; q0 += v0 * v0; s1 += v1; q1 += v1 * v1;
    }
    atomicAdd(&sm_s[f0], s0); atomicAdd(&sm_s[f0 + 1], s1);
    atomicAdd(&sm_q[f0], q0); atomicAdd(&sm_q[f0 + 1], q1);
    __syncthreads();
    if (t < D_H) {
        atomicAdd(stats + t, sm_s[t]);
        atomicAdd(stats + D_H + t, sm_q[t]);
    }
}

// ---------------------------------------------------------------------------
// Fused L1-recompute + BN1 + ReLU + 128-wide aggregation -> bf16.
// Per edge: gather agg0[s] (20 B broadcast), recompute 8 owned features of
// x1[s] in fp32, bnrelu, accumulate. 16 nodes/block, 16 lanes/node.
// ---------------------------------------------------------------------------
__global__ __launch_bounds__(256) void k_agg_l1(const float* __restrict__ agg,
                                                const float* __restrict__ W1,
                                                const float* __restrict__ b1,
                                                const float* __restrict__ stats,
                                                const float* __restrict__ g,
                                                const float* __restrict__ be,
                                                const int* __restrict__ rowptr,
                                                const int2* __restrict__ csr,
                                                const float* __restrict__ dis,
                                                unsigned short* __restrict__ outb)
{
    int t = threadIdx.x;
    int n = blockIdx.x * 16 + (t >> 4);
    int f0 = (t & 15) * 8;
    if (n >= N_NODES) return;
    // per-lane weights: W1[k][f0..f0+8), bias, BN params
    float wl[D_IN][8];
#pragma unroll
    for (int k = 0; k < D_IN; ++k) {
        float4 wlo = *(const float4*)(W1 + k * D_H + f0);
        float4 whi = *(const float4*)(W1 + k * D_H + f0 + 4);
        wl[k][0] = wlo.x; wl[k][1] = wlo.y; wl[k][2] = wlo.z; wl[k][3] = wlo.w;
        wl[k][4] = whi.x; wl[k][5] = whi.y; wl[k][6] = whi.z; wl[k][7] = whi.w;
    }
    float bv[8], sc[8], sh[8];
    const float inv = 1.0f / N_NODES;
#pragma unroll
    for (int j = 0; j < 8; ++j) {
        bv[j] = b1[f0 + j];
        float m = stats[f0 + j] * inv;
        float var = stats[D_H + f0 + j] * inv - m * m;
        sc[j] = rsqrtf(var + BN_EPS) * g[f0 + j];
        sh[j] = be[f0 + j] - m * sc[j];
    }
    float dn = dis[n];
    float acc[8];
    {   // self term (weight dn)
        float4 a03 = *(const float4*)(agg + (size_t)n * 8);
        float a4 = agg[(size_t)n * 8 + 4];
#pragma unroll
        for (int j = 0; j < 8; ++j) {
            float v = bv[j] + wl[0][j] * a03.x + wl[1][j] * a03.y
                    + wl[2][j] * a03.z + wl[3][j] * a03.w + wl[4][j] * a4;
            acc[j] = dn * fmaxf(v * sc[j] + sh[j], 0.f);
        }
    }
    int e = rowptr[n], e1 = rowptr[n + 1];
    for (; e + 2 <= e1; e += 2) {
        int2 p0 = csr[e], p1 = csr[e + 1];
        float w0 = __builtin_bit_cast(float, p0.y);
        float w1 = __builtin_bit_cast(float, p1.y);
        float4 x0 = *(const float4*)(agg + (size_t)p0.x * 8);
        float x04 = agg[(size_t)p0.x * 8 + 4];
        float4 x1 = *(const float4*)(agg + (size_t)p1.x * 8);
        float x14 = agg[(size_t)p1.x * 8 + 4];
#pragma unroll
        for (int j = 0; j < 8; ++j) {
            float v0 = bv[j] + wl[0][j] * x0.x + wl[1][j] * x0.y
                     + wl[2][j] * x0.z + wl[3][j] * x0.w + wl[4][j] * x04;
            float v1 = bv[j] + wl[0][j] * x1.x + wl[1][j] * x1.y
                     + wl[2][j] * x1.z + wl[3][j] * x1.w + wl[4][j] * x14;
            acc[j] += w0 * fmaxf(v0 * sc[j] + sh[j], 0.f)
                    + w1 * fmaxf(v1 * sc[j] + sh[j], 0.f);
        }
    }
    for (; e < e1; ++e) {
        int2 pk = csr[e];
        float pn = __builtin_bit_cast(float, pk.y);
        float4 x0 = *(const float4*)(agg + (size_t)pk.x * 8);
        float x04 = agg[(size_t)pk.x * 8 + 4];
#pragma unroll
        for (int j = 0; j < 8; ++j) {
            float v = bv[j] + wl[0][j] * x0.x + wl[1][j] * x0.y
                    + wl[2][j] * x0.z + wl[3][j] * x0.w + wl[4][j] * x04;
            acc[j] += pn * fmaxf(v * sc[j] + sh[j], 0.f);
        }
    }
    uint4 o;
    o.x = (unsigned)f2bfb(dn * acc[0]) | ((unsigned)f2bfb(dn * acc[1]) << 16);
    o.y = (unsigned)f2bfb(dn * acc[2]) | ((unsigned)f2bfb(dn * acc[3]) << 16);
    o.z = (unsigned)f2bfb(dn * acc[4]) | ((unsigned)f2bfb(dn * acc[5]) << 16);
    o.w = (unsigned)f2bfb(dn * acc[6]) | ((unsigned)f2bfb(dn * acc[7]) << 16);
    *(uint4*)(outb + (size_t)n * D_H + f0) = o;
}

// ---------------------------------------------------------------------------
// MFMA GEMM, LDS-staged B: C_bf16 = A_bf16 @ W + bias (pre-BN), fused stats.
// ---------------------------------------------------------------------------
__global__ __launch_bounds__(256) void k_gemm_mf(const unsigned short* __restrict__ A,
                                                 const unsigned short* __restrict__ Bt,
                                                 const float* __restrict__ bias,
                                                 unsigned short* __restrict__ C,
                                                 float* __restrict__ stats)
{
    __shared__ uint4 ldsB[2048];          // 32 KB fragment-major B
    __shared__ float sm_s[D_H], sm_q[D_H];
    int t = threadIdx.x;
    if (t < D_H) { sm_s[t] = 0.f; sm_q[t] = 0.f; }
    stage_b(Bt, ldsB, t);
    int wave = t >> 6, lane = t & 63;
    int m = lane & 15, quad = lane >> 4;
    int r0 = blockIdx.x * 64 + wave * 16;
    int arow = r0 + m < N_NODES ? r0 + m : N_NODES - 1;
    const bf16x8* ap = (const bf16x8*)(A + (size_t)arow * D_H + quad * 8);
    bf16x8 af[4];
#pragma unroll
    for (int ks = 0; ks < 4; ++ks) af[ks] = ap[ks * 4];
    __syncthreads();
    const bf16x8* bf = (const bf16x8*)ldsB;       // [fid*64 + lane]
    f32x4 acc[8];
#pragma unroll
    for (int ct = 0; ct < 8; ++ct) acc[ct] = (f32x4)(0.f);
#pragma unroll
    for (int ks = 0; ks < 4; ++ks) {
#pragma unroll
        for (int ct = 0; ct < 8; ++ct) {
            acc[ct] = __builtin_amdgcn_mfma_f32_16x16x32_bf16(
                af[ks], bf[(ct * 4 + ks) * 64 + lane], acc[ct], 0, 0, 0);
        }
    }
#pragma unroll
    for (int ct = 0; ct < 8; ++ct) {
        int col = ct * 16 + m;
        float bvv = bias[col];
        float s = 0.f, q = 0.f;
#pragma unroll
        for (int r = 0; r < 4; ++r) {
            int rr = r0 + quad * 4 + r;
            if (rr < N_NODES) {
                float v = acc[ct][r] + bvv;
                C[(size_t)rr * D_H + col] = f2bfb(v);
                s += v; q += v * v;
            }
        }
        atomicAdd(&sm_s[col], s);
        atomicAdd(&sm_q[col], q);
    }
    __syncthreads();
    if (t < D_H) {
        atomicAdd(stats + t, sm_s[t]);
        atomicAdd(stats + D_H + t, sm_q[t]);
    }
}

// ---------------------------------------------------------------------------
// MFMA dual GEMM with fused BN2+ReLU on the A fragments.
// mu -> out[0:N*128), log_std -> out[N*128:). fp32 out.
// ---------------------------------------------------------------------------
__global__ __launch_bounds__(256) void k_gemm_out_mf(const unsigned short* __restrict__ A,
                                                     const float* __restrict__ stats,
                                                     const float* __restrict__ g,
                                                     const float* __restrict__ be,
                                                     const unsigned short* __restrict__ Btmu,
                                                     const float* __restrict__ bmu,
                                                     const unsigned short* __restrict__ Btls,
                                                     const float* __restrict__ bls,
                                                     float* __restrict__ out)
{
    __shared__ uint4 ldsB[2048];          // 32 KB fragment-major B
    int t = threadIdx.x;
    int wave = t >> 6, lane = t & 63;
    int m = lane & 15, quad = lane >> 4;
    int r0 = blockIdx.x * 64 + wave * 16;
    int arow = r0 + m < N_NODES ? r0 + m : N_NODES - 1;
    const unsigned short* arowp = A + (size_t)arow * D_H + quad * 8;
    const float inv = 1.0f / N_NODES;
    bf16x8 af[4];
#pragma unroll
    for (int ks = 0; ks < 4; ++ks) {
        uint4 av = *(const uint4*)(arowp + ks * 32);
        float vals[8] = { bflo(av.x), bfhi(av.x), bflo(av.y), bfhi(av.y),
                          bflo(av.z), bfhi(av.z), bflo(av.w), bfhi(av.w) };
        int fb = quad * 8 + ks * 32;
        unsigned short o[8];
#pragma unroll
        for (int j = 0; j < 8; ++j) {
            int f = fb + j;
            float mm = stats[f] * inv;
            float var = stats[D_H + f] * inv - mm * mm;
            float scv = rsqrtf(var + BN_EPS) * g[f];
            float shv = be[f] - mm * scv;
            o[j] = f2bfb(fmaxf(vals[j] * scv + shv, 0.f));
        }
        uint4 pk;
        pk.x = (unsigned)o[0] | ((unsigned)o[1] << 16);
        pk.y = (unsigned)o[2] | ((unsigned)o[3] << 16);
        pk.z = (unsigned)o[4] | ((unsigned)o[5] << 16);
        pk.w = (unsigned)o[6] | ((unsigned)o[7] << 16);
        af[ks] = __builtin_bit_cast(bf16x8, pk);
    }
    const bf16x8* bf = (const bf16x8*)ldsB;
#pragma unroll
    for (int half = 0; half < 2; ++half) {
        if (half) __syncthreads();        // protect restage vs prior reads
        stage_b(half ? Btls : Btmu, ldsB, t);
        __syncthreads();
        const float* bias = half ? bls : bmu;
        float* C = out + (half ? (size_t)N_NODES * D_H : 0);
        f32x4 acc[8];
#pragma unroll
        for (int ct = 0; ct < 8; ++ct) acc[ct] = (f32x4)(0.f);
#pragma unroll
        for (int ks = 0; ks < 4; ++ks) {
#pragma unroll
            for (int ct = 0; ct < 8; ++ct) {
                acc[ct] = __builtin_amdgcn_mfma_f32_16x16x32_bf16(
                    af[ks], bf[(ct * 4 + ks) * 64 + lane], acc[ct], 0, 0, 0);
            }
        }
#pragma unroll
        for (int ct = 0; ct < 8; ++ct) {
            int col = ct * 16 + m;
            float bvv = bias[col];
#pragma unroll
            for (int r = 0; r < 4; ++r) {
                int rr = r0 + quad * 4 + r;
                if (rr < N_NODES)
                    C[(size_t)rr * D_H + col] = acc[ct][r] + bvv;
            }
        }
    }
}

// ---------------------------------------------------------------------------
extern "C" void kernel_launch(void* const* d_in, const int* in_sizes, int n_in,
                              void* d_out, int out_size, void* d_ws, size_t ws_size,
                              hipStream_t stream)
{
    const float* h   = (const float*)d_in[0];
    const int*   eidx = (const int*)d_in[1];
    const float* ew  = (const float*)d_in[2];
    const float* g0  = (const float*)d_in[3];
    const float* be0 = (const float*)d_in[4];
    const float* W1  = (const float*)d_in[5];
    const float* b1  = (const float*)d_in[6];
    const float* g1  = (const float*)d_in[7];
    const float* be1 = (const float*)d_in[8];
    const float* W2  = (const float*)d_in[9];
    const float* b2  = (const float*)d_in[10];
    const float* g2  = (const float*)d_in[11];
    const float* be2 = (const float*)d_in[12];
    const float* Wmu = (const float*)d_in[13];
    const float* bmu = (const float*)d_in[14];
    const float* Wls = (const float*)d_in[15];
    const float* bls = (const float*)d_in[16];
    const int* srcv = eidx;
    const int* dstv = eidx + N_EDGES;
    float* out = (float*)d_out;

    char* ws = (char*)d_ws;
    size_t off = 0;
    auto alloc = [&](size_t bytes) -> char* {
        char* p = ws + off;
        off += (bytes + 255) & ~(size_t)255;
        return p;
    };
    float* stats0  = (float*)alloc(16 * 4);
    float* stats1  = (float*)alloc(256 * 4);
    float* stats2  = (float*)alloc(256 * 4);
    unsigned long long* degcnt = (unsigned long long*)alloc(N_NODES * 8);
    size_t zero_bytes = off;                 // everything above must start at 0
    int*   rowptr  = (int*)  alloc((N_NODES + 1) * 4);
    float* dis     = (float*)alloc(N_NODES * 4);
    int*   rank    = (int*)  alloc((size_t)N_EDGES * 4);
    int*   blocksums = (int*)alloc(256 * 4);
    int2*  csr     = (int2*) alloc((size_t)N_EDGES * 8);
    float* agg0    = (float*)alloc((size_t)N_NODES * 8 * 4);               // stride-8 padded
    unsigned short* aggh = (unsigned short*)alloc((size_t)N_NODES * D_H * 2);  // bf16 agg
    unsigned short* c2h  = (unsigned short*)alloc((size_t)N_NODES * D_H * 2);  // bf16 pre-BN2
    unsigned short* Wt2   = (unsigned short*)alloc(D_H * D_H * 2);
    unsigned short* Wtmu  = (unsigned short*)alloc(D_H * D_H * 2);
    unsigned short* Wtls  = (unsigned short*)alloc(D_H * D_H * 2);
    (void)ws_size; (void)in_sizes; (void)n_in; (void)out_size;

    hipMemsetAsync(d_ws, 0, zero_bytes, stream);

    k_prep<<<192 + SCAN_BLOCKS + DEG_BLOCKS, 256, 0, stream>>>(
        W2, Wmu, Wls, Wt2, Wtmu, Wtls, h, stats0, dstv, ew, degcnt, rank);
    k_scan1<<<SCAN_BLOCKS, 256, 0, stream>>>(degcnt, dis, blocksums);
    k_scan3<<<SCAN_BLOCKS, 256, 0, stream>>>(degcnt, rowptr, blocksums);
    k_fill<<<DEG_BLOCKS, 256, 0, stream>>>(srcv, dstv, ew, dis, rowptr, rank, csr);
    k_agg0<<<SCAN_BLOCKS, 256, 0, stream>>>(h, stats0, g0, be0, rowptr, csr, dis, agg0);
    k_l1<<<512, 256, 0, stream>>>(agg0, W1, b1, stats1);
    k_agg_l1<<<(N_NODES + 15) / 16, 256, 0, stream>>>(agg0, W1, b1, stats1, g1, be1,
                                                      rowptr, csr, dis, aggh);
    k_gemm_mf<<<(N_NODES + 63) / 64, 256, 0, stream>>>(aggh, Wt2, b2, c2h, stats2);
    k_gemm_out_mf<<<(N_NODES + 63) / 64, 256, 0, stream>>>(c2h, stats2, g2, be2,
                                                           Wtmu, bmu, Wtls, bls, out);
}

// Round 9
// 287.870 us; speedup vs baseline: 1.0458x; 1.0458x over previous
//
#include <hip/hip_runtime.h>

#define N_NODES 50000
#define N_EDGES 600000
#define D_IN 5
#define D_H 128
#define BN_EPS 1e-5f
#define SCAN_BLOCKS ((N_NODES + 255) / 256)   // 196
#define DEG_BLOCKS ((N_EDGES + 255) / 256)    // 2344
#define FIX_SCALE 16777216.0f                  // 2^24
#define FIX_INV   (1.0f / 16777216.0f)

typedef __bf16 bf16x8 __attribute__((ext_vector_type(8)));
typedef float  f32x4  __attribute__((ext_vector_type(4)));

__device__ inline unsigned short f2bfb(float f) {          // fp32 -> bf16 bits, RNE
    unsigned u = __builtin_bit_cast(unsigned, f);
    unsigned r = u + 0x7fffu + ((u >> 16) & 1u);
    return (unsigned short)(r >> 16);
}
__device__ inline float bflo(unsigned u) { return __builtin_bit_cast(float, u << 16); }
__device__ inline float bfhi(unsigned u) { return __builtin_bit_cast(float, u & 0xffff0000u); }

// ---------------------------------------------------------------------------
// Stage Bt[128][128] bf16 into LDS fragment-major: frag fid=ct*4+ks at
// fid*1024 bytes; lane l's 16 B at fid*1024+l*16.
// ---------------------------------------------------------------------------
__device__ inline void stage_b(const unsigned short* __restrict__ Bt,
                               uint4* __restrict__ lds, int t)
{
#pragma unroll
    for (int i = 0; i < 8; ++i) {
        int slot = i * 256 + t;          // 0..2047
        int fid = slot >> 6;
        int l = slot & 63;
        int row = (fid >> 2) * 16 + (l & 15);
        int boff = ((l >> 4) * 16 + (fid & 3) * 64) >> 1;   // in shorts
        lds[slot] = *(const uint4*)(Bt + row * D_H + boff);
    }
}

// ---------------------------------------------------------------------------
// Fused prep: [0,192) weight transpose+bf16; [192,192+SCAN_BLOCKS) BN0 stats;
// rest: per-edge u64 deg/count atomic + rank capture.
// ---------------------------------------------------------------------------
__global__ __launch_bounds__(256) void k_prep(const float* __restrict__ W2,
                                              const float* __restrict__ Wmu,
                                              const float* __restrict__ Wls,
                                              unsigned short* __restrict__ T2,
                                              unsigned short* __restrict__ Tmu,
                                              unsigned short* __restrict__ Tls,
                                              const float* __restrict__ h,
                                              float* __restrict__ stats0,
                                              const int* __restrict__ dst,
                                              const float* __restrict__ w,
                                              unsigned long long* __restrict__ degcnt,
                                              int* __restrict__ rank)
{
    __shared__ float ss[D_IN], sq[D_IN];
    int b = blockIdx.x;
    int t = threadIdx.x;
    if (b < 192) {
        int mat = b >> 6;
        int idx = (b & 63) * 256 + t;   // < 16384
        const float* W = (mat == 0) ? W2 : (mat == 1) ? Wmu : Wls;
        unsigned short* T = (mat == 0) ? T2 : (mat == 1) ? Tmu : Tls;
        int k = idx >> 7, n = idx & 127;
        T[n * D_H + k] = f2bfb(W[idx]);
    } else if (b < 192 + SCAN_BLOCKS) {
        if (t < D_IN) { ss[t] = 0.f; sq[t] = 0.f; }
        __syncthreads();
        int node = (b - 192) * 256 + t;
        float v[D_IN];
#pragma unroll
        for (int f = 0; f < D_IN; ++f)
            v[f] = (node < N_NODES) ? h[node * D_IN + f] : 0.f;
        int lane = t & 63;
#pragma unroll
        for (int f = 0; f < D_IN; ++f) {
            float s = v[f], q = v[f] * v[f];
            for (int off = 32; off > 0; off >>= 1) {
                s += __shfl_down(s, off);
                q += __shfl_down(q, off);
            }
            if (lane == 0) { atomicAdd(&ss[f], s); atomicAdd(&sq[f], q); }
        }
        __syncthreads();
        if (t < D_IN) {
            atomicAdd(&stats0[t], ss[t]);
            atomicAdd(&stats0[D_IN + t], sq[t]);
        }
    } else {
        int e = (b - 192 - SCAN_BLOCKS) * 256 + t;
        if (e < N_EDGES) {
            int d = dst[e];
            unsigned long long fx = (unsigned long long)(w[e] * FIX_SCALE + 0.5f);
            unsigned long long old = atomicAdd(degcnt + d, (1ull << 40) | fx);
            rank[e] = (int)(old >> 40);
        }
    }
}

// ---------------------------------------------------------------------------
// Scan pass 1: per-block sum of counts -> blocksums (raw); dis = rsqrt(deg+1)
// ---------------------------------------------------------------------------
__global__ __launch_bounds__(256) void k_scan1(const unsigned long long* __restrict__ degcnt,
                                               float* __restrict__ dis,
                                               int* __restrict__ blocksums)
{
    __shared__ int sm[256];
    int t = threadIdx.x;
    int i = blockIdx.x * 256 + t;
    int c = 0;
    if (i < N_NODES) {
        unsigned long long v = degcnt[i];
        c = (int)(v >> 40);
        float deg = (float)(v & ((1ull << 40) - 1)) * FIX_INV;
        dis[i] = rsqrtf(deg + 1.0f);
    }
    sm[t] = c;
    __syncthreads();
    for (int off = 128; off > 0; off >>= 1) {
        if (t < off) sm[t] += sm[t + off];
        __syncthreads();
    }
    if (t == 0) blocksums[blockIdx.x] = sm[0];
}

// ---------------------------------------------------------------------------
// Scan pass 2 (merged): every block redundantly scans the 196 raw blocksums
// in LDS to get its own prefix, then does its local node scan -> rowptr.
// ---------------------------------------------------------------------------
__global__ __launch_bounds__(256) void k_scan3(const unsigned long long* __restrict__ degcnt,
                                               int* __restrict__ rowptr,
                                               const int* __restrict__ blocksums)
{
    __shared__ int bs[256];
    __shared__ int sm[256];
    int t = threadIdx.x;
    int bc = (t < SCAN_BLOCKS) ? blocksums[t] : 0;
    bs[t] = bc;
    __syncthreads();
    for (int off = 1; off < 256; off <<= 1) {
        int v = (t >= off) ? bs[t - off] : 0;
        __syncthreads();
        bs[t] += v;
        __syncthreads();
    }
    int prefix = (blockIdx.x == 0) ? 0 : bs[blockIdx.x - 1];
    if (blockIdx.x == SCAN_BLOCKS - 1 && t == 255)
        rowptr[N_NODES] = bs[SCAN_BLOCKS - 1];
    int i = blockIdx.x * 256 + t;
    int c = (i < N_NODES) ? (int)(degcnt[i] >> 40) : 0;
    sm[t] = c;
    __syncthreads();
    for (int off = 1; off < 256; off <<= 1) {
        int v = (t >= off) ? sm[t - off] : 0;
        __syncthreads();
        sm[t] += v;
        __syncthreads();
    }
    if (i < N_NODES)
        rowptr[i] = prefix + sm[t] - c;
}

// ---------------------------------------------------------------------------
// Fill CSR, atomic-free: pos = rowptr[dst] + rank. csr = {src, dis[src]*w}
// ---------------------------------------------------------------------------
__global__ __launch_bounds__(256) void k_fill(const int* __restrict__ src,
                                              const int* __restrict__ dst,
                                              const float* __restrict__ w,
                                              const float* __restrict__ dis,
                                              const int* __restrict__ rowptr,
                                              const int* __restrict__ rank,
                                              int2* __restrict__ csr)
{
    int e = blockIdx.x * blockDim.x + threadIdx.x;
    if (e < N_EDGES) {
        int s = src[e], d = dst[e];
        float pn = dis[s] * w[e];
        int pos = rowptr[d] + rank[e];
        int2 pk;
        pk.x = s;
        pk.y = __builtin_bit_cast(int, pn);
        csr[pos] = pk;
    }
}

// ---------------------------------------------------------------------------
// Aggregate BN0(h) at width 5; agg rows padded to stride 8 for float4 loads.
// agg[n] = dis[n]*(dis[n]*bn(h[n]) + sum pn*bn(h[s]))
// ---------------------------------------------------------------------------
__global__ __launch_bounds__(256) void k_agg0(const float* __restrict__ h,
                                              const float* __restrict__ stats,
                                              const float* __restrict__ g0,
                                              const float* __restrict__ be0,
                                              const int* __restrict__ rowptr,
                                              const int2* __restrict__ csr,
                                              const float* __restrict__ dis,
                                              float* __restrict__ agg)
{
    int n = blockIdx.x * blockDim.x + threadIdx.x;
    if (n >= N_NODES) return;
    float sc[D_IN], sh[D_IN];
#pragma unroll
    for (int f = 0; f < D_IN; ++f) {
        float m = stats[f] * (1.0f / N_NODES);
        float var = stats[D_IN + f] * (1.0f / N_NODES) - m * m;
        sc[f] = rsqrtf(var + BN_EPS) * g0[f];
        sh[f] = be0[f] - m * sc[f];
    }
    float dn = dis[n];
    float acc[D_IN];
#pragma unroll
    for (int f = 0; f < D_IN; ++f)
        acc[f] = dn * (h[n * D_IN + f] * sc[f] + sh[f]);
    int e0 = rowptr[n], e1 = rowptr[n + 1];
    for (int e = e0; e < e1; ++e) {
        int2 pk = csr[e];
        int s = pk.x;
        float pn = __builtin_bit_cast(float, pk.y);
#pragma unroll
        for (int f = 0; f < D_IN; ++f)
            acc[f] += pn * (h[s * D_IN + f] * sc[f] + sh[f]);
    }
#pragma unroll
    for (int f = 0; f < D_IN; ++f)
        agg[(size_t)n * 8 + f] = dn * acc[f];
}

// ---------------------------------------------------------------------------
// Layer-1 skinny GEMM (K=5), bf16 output (pre-BN), fused BN1 stats (fp32).
// MUST be launched with exactly 512 blocks x 256 threads.
// ---------------------------------------------------------------------------
__global__ __launch_bounds__(256) void k_l1(const float* __restrict__ agg,
                                            const float* __restrict__ W1,
                                            const float* __restrict__ b1,
                                            unsigned short* __restrict__ x,
                                            float* __restrict__ stats)
{
    __shared__ float sm_s[D_H], sm_q[D_H];
    int t = threadIdx.x;
    if (t < D_H) { sm_s[t] = 0.f; sm_q[t] = 0.f; }
    __syncthreads();
    int idx0 = blockIdx.x * 256 + t;
    int f0 = (idx0 & 63) * 2;      // feature pair, constant per thread
    float wa[D_IN], wb[D_IN];
#pragma unroll
    for (int k = 0; k < D_IN; ++k) {
        wa[k] = W1[k * D_H + f0];
        wb[k] = W1[k * D_H + f0 + 1];
    }
    float ba = b1[f0], bb = b1[f0 + 1];
    float s0 = 0.f, q0 = 0.f, s1 = 0.f, q1 = 0.f;
    const int stride = 512 * 256;
    for (int idx = idx0; idx < N_NODES * 64; idx += stride) {
        int n = idx >> 6;
        const float* a = agg + (size_t)n * 8;
        float v0 = ba, v1 = bb;
#pragma unroll
        for (int k = 0; k < D_IN; ++k) { v0 += wa[k] * a[k]; v1 += wb[k] * a[k]; }
        ((unsigned*)x)[idx] = (unsigned)f2bfb(v0) | ((unsigned)f2bfb(v1) << 16);
        s0 += v0; q0 += v0 * v0; s1 += v1; q1 += v1 * v1;
    }
    atomicAdd(&sm_s[f0], s0); atomicAdd(&sm_s[f0 + 1], s1);
    atomicAdd(&sm_q[f0], q0); atomicAdd(&sm_q[f0 + 1], q1);
    __syncthreads();
    if (t < D_H) {
        atomicAdd(stats + t, sm_s[t]);
        atomicAdd(stats + D_H + t, sm_q[t]);
    }
}

// ---------------------------------------------------------------------------
// 128-wide aggregation, fused BN1+ReLU, ONE WAVE PER NODE:
// 4 nodes/block, lane owns 2 features -> each edge row-read is a single
// fully-coalesced 256 B wave transaction; loop count = own degree (no
// intra-wave divergence). bf16 in -> bf16 out, fp32 accumulate.
// ---------------------------------------------------------------------------
__global__ __launch_bounds__(256) void k_agg128(const unsigned short* __restrict__ x,
                                                const float* __restrict__ stats,
                                                const float* __restrict__ g,
                                                const float* __restrict__ be,
                                                const int* __restrict__ rowptr,
                                                const int2* __restrict__ csr,
                                                const float* __restrict__ dis,
                                                unsigned short* __restrict__ outb)
{
    int t = threadIdx.x;
    int n = blockIdx.x * 4 + (t >> 6);
    int lane = t & 63;
    int f0 = lane * 2;
    if (n >= N_NODES) return;
    const float inv = 1.0f / N_NODES;
    float m0 = stats[f0] * inv;
    float v0v = stats[D_H + f0] * inv - m0 * m0;
    float sc0 = rsqrtf(v0v + BN_EPS) * g[f0];
    float sh0 = be[f0] - m0 * sc0;
    float m1 = stats[f0 + 1] * inv;
    float v1v = stats[D_H + f0 + 1] * inv - m1 * m1;
    float sc1 = rsqrtf(v1v + BN_EPS) * g[f0 + 1];
    float sh1 = be[f0 + 1] - m1 * sc1;
#define BNR0(v) fmaxf((v) * sc0 + sh0, 0.f)
#define BNR1(v) fmaxf((v) * sc1 + sh1, 0.f)
    float dn = dis[n];
    unsigned hv = *(const unsigned*)(x + (size_t)n * D_H + f0);
    float a0 = dn * BNR0(bflo(hv));
    float a1 = dn * BNR1(bfhi(hv));
    int e = rowptr[n], e1 = rowptr[n + 1];
    for (; e + 4 <= e1; e += 4) {
        int2 p0 = csr[e + 0], p1 = csr[e + 1], p2 = csr[e + 2], p3 = csr[e + 3];
        float w0 = __builtin_bit_cast(float, p0.y);
        float w1 = __builtin_bit_cast(float, p1.y);
        float w2 = __builtin_bit_cast(float, p2.y);
        float w3 = __builtin_bit_cast(float, p3.y);
        unsigned v0 = *(const unsigned*)(x + (size_t)p0.x * D_H + f0);
        unsigned v1 = *(const unsigned*)(x + (size_t)p1.x * D_H + f0);
        unsigned v2 = *(const unsigned*)(x + (size_t)p2.x * D_H + f0);
        unsigned v3 = *(const unsigned*)(x + (size_t)p3.x * D_H + f0);
        a0 += w0 * BNR0(bflo(v0)) + w1 * BNR0(bflo(v1))
            + w2 * BNR0(bflo(v2)) + w3 * BNR0(bflo(v3));
        a1 += w0 * BNR1(bfhi(v0)) + w1 * BNR1(bfhi(v1))
            + w2 * BNR1(bfhi(v2)) + w3 * BNR1(bfhi(v3));
    }
    for (; e < e1; ++e) {
        int2 pk = csr[e];
        float pn = __builtin_bit_cast(float, pk.y);
        unsigned v = *(const unsigned*)(x + (size_t)pk.x * D_H + f0);
        a0 += pn * BNR0(bflo(v));
        a1 += pn * BNR1(bfhi(v));
    }
#undef BNR0
#undef BNR1
    unsigned o = (unsigned)f2bfb(dn * a0) | ((unsigned)f2bfb(dn * a1) << 16);
    *(unsigned*)(outb + (size_t)n * D_H + f0) = o;
}

// ---------------------------------------------------------------------------
// MFMA GEMM, LDS-staged B: C_bf16 = A_bf16 @ W + bias (pre-BN), fused stats.
// ---------------------------------------------------------------------------
__global__ __launch_bounds__(256) void k_gemm_mf(const unsigned short* __restrict__ A,
                                                 const unsigned short* __restrict__ Bt,
                                                 const float* __restrict__ bias,
                                                 unsigned short* __restrict__ C,
                                                 float* __restrict__ stats)
{
    __shared__ uint4 ldsB[2048];          // 32 KB fragment-major B
    __shared__ float sm_s[D_H], sm_q[D_H];
    int t = threadIdx.x;
    if (t < D_H) { sm_s[t] = 0.f; sm_q[t] = 0.f; }
    stage_b(Bt, ldsB, t);
    int wave = t >> 6, lane = t & 63;
    int m = lane & 15, quad = lane >> 4;
    int r0 = blockIdx.x * 64 + wave * 16;
    int arow = r0 + m < N_NODES ? r0 + m : N_NODES - 1;
    const bf16x8* ap = (const bf16x8*)(A + (size_t)arow * D_H + quad * 8);
    bf16x8 af[4];
#pragma unroll
    for (int ks = 0; ks < 4; ++ks) af[ks] = ap[ks * 4];
    __syncthreads();
    const bf16x8* bf = (const bf16x8*)ldsB;       // [fid*64 + lane]
    f32x4 acc[8];
#pragma unroll
    for (int ct = 0; ct < 8; ++ct) acc[ct] = (f32x4)(0.f);
#pragma unroll
    for (int ks = 0; ks < 4; ++ks) {
#pragma unroll
        for (int ct = 0; ct < 8; ++ct) {
            acc[ct] = __builtin_amdgcn_mfma_f32_16x16x32_bf16(
                af[ks], bf[(ct * 4 + ks) * 64 + lane], acc[ct], 0, 0, 0);
        }
    }
#pragma unroll
    for (int ct = 0; ct < 8; ++ct) {
        int col = ct * 16 + m;
        float bvv = bias[col];
        float s = 0.f, q = 0.f;
#pragma unroll
        for (int r = 0; r < 4; ++r) {
            int rr = r0 + quad * 4 + r;
            if (rr < N_NODES) {
                float v = acc[ct][r] + bvv;
                C[(size_t)rr * D_H + col] = f2bfb(v);
                s += v; q += v * v;
            }
        }
        atomicAdd(&sm_s[col], s);
        atomicAdd(&sm_q[col], q);
    }
    __syncthreads();
    if (t < D_H) {
        atomicAdd(stats + t, sm_s[t]);
        atomicAdd(stats + D_H + t, sm_q[t]);
    }
}

// ---------------------------------------------------------------------------
// MFMA dual GEMM with fused BN2+ReLU on the A fragments.
// mu -> out[0:N*128), log_std -> out[N*128:). fp32 out.
// ---------------------------------------------------------------------------
__global__ __launch_bounds__(256) void k_gemm_out_mf(const unsigned short* __restrict__ A,
                                                     const float* __restrict__ stats,
                                                     const float* __restrict__ g,
                                                     const float* __restrict__ be,
                                                     const unsigned short* __restrict__ Btmu,
                                                     const float* __restrict__ bmu,
                                                     const unsigned short* __restrict__ Btls,
                                                     const float* __restrict__ bls,
                                                     float* __restrict__ out)
{
    __shared__ uint4 ldsB[2048];          // 32 KB fragment-major B
    int t = threadIdx.x;
    int wave = t >> 6, lane = t & 63;
    int m = lane & 15, quad = lane >> 4;
    int r0 = blockIdx.x * 64 + wave * 16;
    int arow = r0 + m < N_NODES ? r0 + m : N_NODES - 1;
    const unsigned short* arowp = A + (size_t)arow * D_H + quad * 8;
    const float inv = 1.0f / N_NODES;
    bf16x8 af[4];
#pragma unroll
    for (int ks = 0; ks < 4; ++ks) {
        uint4 av = *(const uint4*)(arowp + ks * 32);
        float vals[8] = { bflo(av.x), bfhi(av.x), bflo(av.y), bfhi(av.y),
                          bflo(av.z), bfhi(av.z), bflo(av.w), bfhi(av.w) };
        int fb = quad * 8 + ks * 32;
        unsigned short o[8];
#pragma unroll
        for (int j = 0; j < 8; ++j) {
            int f = fb + j;
            float mm = stats[f] * inv;
            float var = stats[D_H + f] * inv - mm * mm;
            float scv = rsqrtf(var + BN_EPS) * g[f];
            float shv = be[f] - mm * scv;
            o[j] = f2bfb(fmaxf(vals[j] * scv + shv, 0.f));
        }
        uint4 pk;
        pk.x = (unsigned)o[0] | ((unsigned)o[1] << 16);
        pk.y = (unsigned)o[2] | ((unsigned)o[3] << 16);
        pk.z = (unsigned)o[4] | ((unsigned)o[5] << 16);
        pk.w = (unsigned)o[6] | ((unsigned)o[7] << 16);
        af[ks] = __builtin_bit_cast(bf16x8, pk);
    }
    const bf16x8* bf = (const bf16x8*)ldsB;
#pragma unroll
    for (int half = 0; half < 2; ++half) {
        if (half) __syncthreads();        // protect restage vs prior reads
        stage_b(half ? Btls : Btmu, ldsB, t);
        __syncthreads();
        const float* bias = half ? bls : bmu;
        float* C = out + (half ? (size_t)N_NODES * D_H : 0);
        f32x4 acc[8];
#pragma unroll
        for (int ct = 0; ct < 8; ++ct) acc[ct] = (f32x4)(0.f);
#pragma unroll
        for (int ks = 0; ks < 4; ++ks) {
#pragma unroll
            for (int ct = 0; ct < 8; ++ct) {
                acc[ct] = __builtin_amdgcn_mfma_f32_16x16x32_bf16(
                    af[ks], bf[(ct * 4 + ks) * 64 + lane], acc[ct], 0, 0, 0);
            }
        }
#pragma unroll
        for (int ct = 0; ct < 8; ++ct) {
            int col = ct * 16 + m;
            float bvv = bias[col];
#pragma unroll
            for (int r = 0; r < 4; ++r) {
                int rr = r0 + quad * 4 + r;
                if (rr < N_NODES)
                    C[(size_t)rr * D_H + col] = acc[ct][r] + bvv;
            }
        }
    }
}

// ---------------------------------------------------------------------------
extern "C" void kernel_launch(void* const* d_in, const int* in_sizes, int n_in,
                              void* d_out, int out_size, void* d_ws, size_t ws_size,
                              hipStream_t stream)
{
    const float* h   = (const float*)d_in[0];
    const int*   eidx = (const int*)d_in[1];
    const float* ew  = (const float*)d_in[2];
    const float* g0  = (const float*)d_in[3];
    const float* be0 = (const float*)d_in[4];
    const float* W1  = (const float*)d_in[5];
    const float* b1  = (const float*)d_in[6];
    const float* g1  = (const float*)d_in[7];
    const float* be1 = (const float*)d_in[8];
    const float* W2  = (const float*)d_in[9];
    const float* b2  = (const float*)d_in[10];
    const float* g2  = (const float*)d_in[11];
    const float* be2 = (const float*)d_in[12];
    const float* Wmu = (const float*)d_in[13];
    const float* bmu = (const float*)d_in[14];
    const float* Wls = (const float*)d_in[15];
    const float* bls = (const float*)d_in[16];
    const int* srcv = eidx;
    const int* dstv = eidx + N_EDGES;
    float* out = (float*)d_out;

    char* ws = (char*)d_ws;
    size_t off = 0;
    auto alloc = [&](size_t bytes) -> char* {
        char* p = ws + off;
        off += (bytes + 255) & ~(size_t)255;
        return p;
    };
    float* stats0  = (float*)alloc(16 * 4);
    float* stats1  = (float*)alloc(256 * 4);
    float* stats2  = (float*)alloc(256 * 4);
    unsigned long long* degcnt = (unsigned long long*)alloc(N_NODES * 8);
    size_t zero_bytes = off;                 // everything above must start at 0
    int*   rowptr  = (int*)  alloc((N_NODES + 1) * 4);
    float* dis     = (float*)alloc(N_NODES * 4);
    int*   rank    = (int*)  alloc((size_t)N_EDGES * 4);
    int*   blocksums = (int*)alloc(256 * 4);
    int2*  csr     = (int2*) alloc((size_t)N_EDGES * 8);
    float* agg0    = (float*)alloc((size_t)N_NODES * 8 * 4);               // stride-8 padded
    unsigned short* x1h  = (unsigned short*)alloc((size_t)N_NODES * D_H * 2);  // bf16 pre-BN1
    unsigned short* aggh = (unsigned short*)alloc((size_t)N_NODES * D_H * 2);  // bf16 agg
    unsigned short* c2h  = (unsigned short*)alloc((size_t)N_NODES * D_H * 2);  // bf16 pre-BN2
    unsigned short* Wt2   = (unsigned short*)alloc(D_H * D_H * 2);
    unsigned short* Wtmu  = (unsigned short*)alloc(D_H * D_H * 2);
    unsigned short* Wtls  = (unsigned short*)alloc(D_H * D_H * 2);
    (void)ws_size; (void)in_sizes; (void)n_in; (void)out_size;

    hipMemsetAsync(d_ws, 0, zero_bytes, stream);

    k_prep<<<192 + SCAN_BLOCKS + DEG_BLOCKS, 256, 0, stream>>>(
        W2, Wmu, Wls, Wt2, Wtmu, Wtls, h, stats0, dstv, ew, degcnt, rank);
    k_scan1<<<SCAN_BLOCKS, 256, 0, stream>>>(degcnt, dis, blocksums);
    k_scan3<<<SCAN_BLOCKS, 256, 0, stream>>>(degcnt, rowptr, blocksums);
    k_fill<<<DEG_BLOCKS, 256, 0, stream>>>(srcv, dstv, ew, dis, rowptr, rank, csr);
    k_agg0<<<SCAN_BLOCKS, 256, 0, stream>>>(h, stats0, g0, be0, rowptr, csr, dis, agg0);
    k_l1<<<512, 256, 0, stream>>>(agg0, W1, b1, x1h, stats1);
    k_agg128<<<(N_NODES + 3) / 4, 256, 0, stream>>>(x1h, stats1, g1, be1,
                                                    rowptr, csr, dis, aggh);
    k_gemm_mf<<<(N_NODES + 63) / 64, 256, 0, stream>>>(aggh, Wt2, b2, c2h, stats2);
    k_gemm_out_mf<<<(N_NODES + 63) / 64, 256, 0, stream>>>(c2h, stats2, g2, be2,
                                                           Wtmu, bmu, Wtls, bls, out);
}